// Round 4
// baseline (239.334 us; speedup 1.0000x reference)
//
#include <hip/hip_runtime.h>
#include <stdint.h>
#include <math.h>

#define E_DIM 1024
#define W_DIM 1024
#define EW 1048576L   // 1024*1024

typedef _Float16 h16;
typedef __attribute__((ext_vector_type(8))) _Float16 h8;
typedef __attribute__((ext_vector_type(4))) float f4;

__device__ __forceinline__ void async_copy16(h16* lds, const h16* g) {
    __builtin_amdgcn_global_load_lds(
        (const __attribute__((address_space(1))) void*)g,
        (__attribute__((address_space(3))) void*)lds, 16, 0, 0);
}

// ---------------------------------------------------------------------------
// prep: z<12 -> transpose-convert x [12][E][W] fp32 -> [12][W][E] fp16;
//       z>=12 -> convert weight (z-12) fp32 -> fp16 into wh[LK|LQ|LV|M].
// ---------------------------------------------------------------------------
__global__ __launch_bounds__(256) void prep(
    const float* __restrict__ x, const float* __restrict__ LK,
    const float* __restrict__ LQ, const float* __restrict__ LV,
    const float* __restrict__ Mw, h16* __restrict__ xt, h16* __restrict__ wh)
{
    __shared__ float Ts[64][65];
    const int z = blockIdx.z;
    const int t = threadIdx.x;
    if (z < 12) {
        const float* src = x + (long)z * EW;   // [e][w]
        h16* dst = xt + (long)z * EW;          // [w][e]
        const int e0 = blockIdx.y * 64, w0 = blockIdx.x * 64;
        const int r = t >> 4, c4 = (t & 15) * 4;
        #pragma unroll
        for (int p = 0; p < 4; ++p) {
            float4 v = *reinterpret_cast<const float4*>(src + (long)(e0 + r + p * 16) * W_DIM + w0 + c4);
            Ts[c4 + 0][r + p * 16] = v.x;
            Ts[c4 + 1][r + p * 16] = v.y;
            Ts[c4 + 2][r + p * 16] = v.z;
            Ts[c4 + 3][r + p * 16] = v.w;
        }
        __syncthreads();
        #pragma unroll
        for (int p = 0; p < 4; ++p) {
            int wr = r + p * 16;
            union { h16 h[4]; uint2 u; } o;
            o.h[0] = (h16)Ts[wr][c4 + 0];
            o.h[1] = (h16)Ts[wr][c4 + 1];
            o.h[2] = (h16)Ts[wr][c4 + 2];
            o.h[3] = (h16)Ts[wr][c4 + 3];
            *reinterpret_cast<uint2*>(dst + (long)(w0 + wr) * E_DIM + e0 + c4) = o.u;
        }
    } else {
        const float* srcs[4] = {LK, LQ, LV, Mw};
        const float* s = srcs[z - 12];
        h16* o = wh + (long)(z - 12) * EW;
        long base = ((long)(blockIdx.y * 16 + blockIdx.x)) * 1024 + t;  // float4 idx
        #pragma unroll
        for (int k = 0; k < 4; ++k) {
            long i = base + k * 256;
            float4 v = reinterpret_cast<const float4*>(s)[i];
            union { h16 h[4]; uint2 u; } u;
            u.h[0] = (h16)v.x; u.h[1] = (h16)v.y; u.h[2] = (h16)v.z; u.h[3] = (h16)v.w;
            reinterpret_cast<uint2*>(o)[i] = u.u;
        }
    }
}

// ---------------------------------------------------------------------------
// Fused projection GEMMs (K, Q, V), z = proj*4 + batch. 128x128 tile, BK=64.
// DOUBLE-BUFFERED: issue tile i+1's DMA after the single barrier, compute
// tile i meanwhile -> load latency hidden under MFMA (was fully exposed).
// ---------------------------------------------------------------------------
__global__ __launch_bounds__(256) void gemm_proj3(
    const h16* __restrict__ xh, const h16* __restrict__ Wts,
    h16* __restrict__ KQV)
{
    __shared__ h16 As[2][128 * 64];
    __shared__ h16 Bs[2][128 * 64];

    const int t = threadIdx.x;
    const int wave = t >> 6, lane = t & 63;
    const int quad = lane >> 4, l16 = lane & 15;
    const int m0 = blockIdx.y * 128, n0 = blockIdx.x * 128;
    const int wm = (wave >> 1) * 64, wn = (wave & 1) * 64;

    const int proj = blockIdx.z >> 2, bz = blockIdx.z & 3;
    const h16 *A, *Bt; h16* C;
    if (proj == 0)      { A = xh + bz * EW;       Bt = Wts;          C = KQV + bz * EW; }
    else if (proj == 1) { A = xh + (4 + bz) * EW; Bt = Wts + EW;     C = KQV + (4 + bz) * EW; }
    else                { A = Wts + 2 * EW;       Bt = xh + (8 + bz) * EW; C = KQV + (8 + bz) * EW; }

    f4 acc[4][4] = {};

    // prologue: stage tile 0 into buf 0
    #pragma unroll
    for (int j = 0; j < 4; ++j) {
        int g = j * 256 + t, row = g >> 3, cg = (g & 7) ^ (row & 7);
        async_copy16(&As[0][g * 8], A  + (long)(m0 + row) * E_DIM + cg * 8);
        async_copy16(&Bs[0][g * 8], Bt + (long)(n0 + row) * E_DIM + cg * 8);
    }

    for (int i = 0; i < 16; ++i) {
        __syncthreads();   // drains tile i's DMA (had full prev compute to land)
        if (i + 1 < 16) {
            const int k1 = (i + 1) * 64, nb = (i + 1) & 1;
            #pragma unroll
            for (int j = 0; j < 4; ++j) {
                int g = j * 256 + t, row = g >> 3, cg = (g & 7) ^ (row & 7);
                async_copy16(&As[nb][g * 8], A  + (long)(m0 + row) * E_DIM + k1 + cg * 8);
                async_copy16(&Bs[nb][g * 8], Bt + (long)(n0 + row) * E_DIM + k1 + cg * 8);
            }
        }
        const h16* as = As[i & 1];
        const h16* bs = Bs[i & 1];

        h8 av[4][2], bv[4][2];
        #pragma unroll
        for (int ii = 0; ii < 4; ++ii) {
            int ra = wm + ii * 16 + l16, rb = wn + ii * 16 + l16;
            #pragma unroll
            for (int c = 0; c < 2; ++c) {
                av[ii][c] = *reinterpret_cast<const h8*>(&as[(ra * 8 + ((c * 4 + quad) ^ (l16 & 7))) * 8]);
                bv[ii][c] = *reinterpret_cast<const h8*>(&bs[(rb * 8 + ((c * 4 + quad) ^ (l16 & 7))) * 8]);
            }
        }
        #pragma unroll
        for (int c = 0; c < 2; ++c)
            #pragma unroll
            for (int mt = 0; mt < 4; ++mt)
                #pragma unroll
                for (int nt = 0; nt < 4; ++nt)
                    acc[mt][nt] = __builtin_amdgcn_mfma_f32_16x16x32_f16(av[mt][c], bv[nt][c], acc[mt][nt], 0, 0, 0);
    }

    #pragma unroll
    for (int mt = 0; mt < 4; ++mt)
        #pragma unroll
        for (int i = 0; i < 4; ++i) {
            int m = m0 + wm + mt * 16 + quad * 4 + i;
            #pragma unroll
            for (int nt = 0; nt < 4; ++nt)
                C[(long)m * W_DIM + n0 + wn + nt * 16 + l16] = (h16)acc[mt][nt][i];
        }
}

// ---------------------------------------------------------------------------
// Output GEMM, batch-fused: out = M[1024x1024] x Ao[4096x1024]^T (+bias).
// Same double-buffered stage-ahead structure.
// ---------------------------------------------------------------------------
__global__ __launch_bounds__(256) void gemm_out(
    const h16* __restrict__ A, const h16* __restrict__ Bt,
    float* __restrict__ C, const float* __restrict__ bias)
{
    __shared__ h16 As[2][64 * 64];
    __shared__ h16 Bs[2][128 * 64];

    const int t = threadIdx.x;
    const int wave = t >> 6, lane = t & 63;
    const int quad = lane >> 4, l16 = lane & 15;
    const int m0 = blockIdx.y * 64, n0 = blockIdx.x * 128;
    const int wm = (wave >> 1) * 32, wn = (wave & 1) * 64;

    f4 acc[2][4] = {};

    // prologue: stage tile 0
    #pragma unroll
    for (int j = 0; j < 2; ++j) {
        int g = j * 256 + t, row = g >> 3, cg = (g & 7) ^ (row & 7);
        async_copy16(&As[0][g * 8], A + (long)(m0 + row) * E_DIM + cg * 8);
    }
    #pragma unroll
    for (int j = 0; j < 4; ++j) {
        int g = j * 256 + t, row = g >> 3, cg = (g & 7) ^ (row & 7);
        async_copy16(&Bs[0][g * 8], Bt + (long)(n0 + row) * E_DIM + cg * 8);
    }

    for (int i = 0; i < 16; ++i) {
        __syncthreads();
        if (i + 1 < 16) {
            const int k1 = (i + 1) * 64, nb = (i + 1) & 1;
            #pragma unroll
            for (int j = 0; j < 2; ++j) {
                int g = j * 256 + t, row = g >> 3, cg = (g & 7) ^ (row & 7);
                async_copy16(&As[nb][g * 8], A + (long)(m0 + row) * E_DIM + k1 + cg * 8);
            }
            #pragma unroll
            for (int j = 0; j < 4; ++j) {
                int g = j * 256 + t, row = g >> 3, cg = (g & 7) ^ (row & 7);
                async_copy16(&Bs[nb][g * 8], Bt + (long)(n0 + row) * E_DIM + k1 + cg * 8);
            }
        }
        const h16* as = As[i & 1];
        const h16* bs = Bs[i & 1];

        h8 av[2][2], bv[4][2];
        #pragma unroll
        for (int c = 0; c < 2; ++c) {
            #pragma unroll
            for (int mt = 0; mt < 2; ++mt) {
                int r = wm + mt * 16 + l16;
                av[mt][c] = *reinterpret_cast<const h8*>(&as[(r * 8 + ((c * 4 + quad) ^ (l16 & 7))) * 8]);
            }
            #pragma unroll
            for (int nt = 0; nt < 4; ++nt) {
                int r = wn + nt * 16 + l16;
                bv[nt][c] = *reinterpret_cast<const h8*>(&bs[(r * 8 + ((c * 4 + quad) ^ (l16 & 7))) * 8]);
            }
        }
        #pragma unroll
        for (int c = 0; c < 2; ++c)
            #pragma unroll
            for (int mt = 0; mt < 2; ++mt)
                #pragma unroll
                for (int nt = 0; nt < 4; ++nt)
                    acc[mt][nt] = __builtin_amdgcn_mfma_f32_16x16x32_f16(av[mt][c], bv[nt][c], acc[mt][nt], 0, 0, 0);
    }

    #pragma unroll
    for (int mt = 0; mt < 2; ++mt)
        #pragma unroll
        for (int i = 0; i < 4; ++i) {
            int m = m0 + wm + mt * 16 + quad * 4 + i;
            float bv_ = bias ? bias[m] : 0.f;
            #pragma unroll
            for (int nt = 0; nt < 4; ++nt) {
                int n = n0 + wn + nt * 16 + l16;   // n = b*1024 + w
                C[(long)(n >> 10) * EW + (long)m * W_DIM + (n & 1023)] = acc[mt][nt][i] + bv_;
            }
        }
}

// ---------------------------------------------------------------------------
// MFMA flash attention (softmax over q) — Round-1 staged structure (41 us)
// + DEFERRED PV: PV of tile t-1 issues right after S-MFMA(t), so its MFMAs
// overlap softmax(t)'s VALU work. O-rescale correctly follows the deferred
// add. V fragments of tile t persist in registers across the barrier.
// ---------------------------------------------------------------------------
__global__ __launch_bounds__(256) void attn_mfma(
    const h16* __restrict__ Kt, const h16* __restrict__ Qt,
    const h16* __restrict__ V, h16* __restrict__ AoT)
{
    __shared__ h16 Qs[2][64 * 64];   // [q][d] swizzled granules
    __shared__ h16 Vs[2][64 * 64];   // [d][q] swizzled granules
    __shared__ h16 Ps[4][32 * 64];   // per-wave P^T [k32][q64] swizzled granules

    const int t = threadIdx.x, wave = t >> 6, lane = t & 63;
    const int quad = lane >> 4, l16 = lane & 15;
    const int y = blockIdx.y;
    const int b = y >> 4, h = y & 15;
    const int cxor = (y & 7) ^ (((y >> 5) & 1) ? 7 : 0);
    const int ktb = (int)blockIdx.x ^ cxor;     // 0..7; id & id+256 complementary
    const int nit = 2 * ktb + 2;                // staging iterations (block-wide)
    const int kwave = ktb * 128 + wave * 32;    // wave's first k column
    const int kc0 = kwave + l16, kc1 = kc0 + 16;
    const int nitw = ((kwave + 31) >> 6) + 1;   // active iters: nit (waves 2,3) or nit-1

    const h16* Ktb_ = Kt + (long)b * EW + h * 64;
    const h16* Qtb  = Qt + (long)b * EW + h * 64;
    const h16* Vb   = V  + (long)b * EW + (long)(h * 64) * W_DIM;
    h16* Pw = &Ps[wave][0];

    // K in registers: group g, half c -> K^T[kc_g][c*32 + quad*8 + j]
    h8 kb00 = *reinterpret_cast<const h8*>(Ktb_ + (long)kc0 * E_DIM + quad * 8);
    h8 kb01 = *reinterpret_cast<const h8*>(Ktb_ + (long)kc0 * E_DIM + 32 + quad * 8);
    h8 kb10 = *reinterpret_cast<const h8*>(Ktb_ + (long)kc1 * E_DIM + quad * 8);
    h8 kb11 = *reinterpret_cast<const h8*>(Ktb_ + (long)kc1 * E_DIM + 32 + quad * 8);

    // stage tile 0 into buf 0
    #pragma unroll
    for (int j = 0; j < 2; ++j) {
        int g = j * 256 + t, row = g >> 3, cg = (g & 7) ^ (row & 7);
        async_copy16(&Qs[0][g * 8], Qtb + (long)row * E_DIM + cg * 8);
        async_copy16(&Vs[0][g * 8], Vb + (long)row * W_DIM + cg * 8);
    }

    const float L2E = 1.442695041f;
    float mr0 = -1e30f, mr1 = -1e30f, ls0 = 0.f, ls1 = 0.f;
    f4 O[4][2] = {};
    h8 vap[4][2];    // V fragments of the previous (deferred) tile

    for (int it = 0; it < nit; ++it) {
        const int q0 = it * 64;
        __syncthreads();   // drains DMA for buf it&1; prev iter's readers done
        if (it + 1 < nit) {
            const int nb = (it + 1) & 1, q1 = q0 + 64;
            #pragma unroll
            for (int j = 0; j < 2; ++j) {
                int g = j * 256 + t, row = g >> 3, cg = (g & 7) ^ (row & 7);
                async_copy16(&Qs[nb][g * 8], Qtb + (long)(q1 + row) * E_DIM + cg * 8);
                async_copy16(&Vs[nb][g * 8], Vb + (long)row * W_DIM + q1 + cg * 8);
            }
        }
        const bool act = it < nitw;
        const h16* qs = Qs[it & 1];
        const h16* vs = Vs[it & 1];

        f4 S0[4], S1[4];
        h8 va[4][2];
        if (act) {
            // V fragments for THIS tile (consumed next iteration)
            #pragma unroll
            for (int dt = 0; dt < 4; ++dt)
                #pragma unroll
                for (int c = 0; c < 2; ++c) {
                    int r = dt * 16 + l16;
                    va[dt][c] = *reinterpret_cast<const h8*>(&vs[(r * 8 + ((c * 4 + quad) ^ (l16 & 7))) * 8]);
                }
            // S^T[q][k] for both k-groups; Q fragments shared
            __builtin_amdgcn_s_setprio(1);
            #pragma unroll
            for (int nt = 0; nt < 4; ++nt) {
                int row = nt * 16 + l16;
                h8 a0 = *reinterpret_cast<const h8*>(&qs[(row * 8 + (quad ^ (l16 & 7))) * 8]);
                h8 a1 = *reinterpret_cast<const h8*>(&qs[(row * 8 + ((4 + quad) ^ (l16 & 7))) * 8]);
                f4 s0 = {}, s1 = {};
                s0 = __builtin_amdgcn_mfma_f32_16x16x32_f16(a0, kb00, s0, 0, 0, 0);
                s1 = __builtin_amdgcn_mfma_f32_16x16x32_f16(a0, kb10, s1, 0, 0, 0);
                s0 = __builtin_amdgcn_mfma_f32_16x16x32_f16(a1, kb01, s0, 0, 0, 0);
                s1 = __builtin_amdgcn_mfma_f32_16x16x32_f16(a1, kb11, s1, 0, 0, 0);
                S0[nt] = s0; S1[nt] = s1;
            }
            __builtin_amdgcn_s_setprio(0);
        }

        // deferred PV(it-1): overlaps softmax(it)'s VALU work below
        if (it > 0 && it - 1 < nitw) {
            __builtin_amdgcn_s_setprio(1);
            #pragma unroll
            for (int c = 0; c < 2; ++c) {
                int sg = ((c * 4 + quad) ^ (l16 & 7)) * 8;
                h8 p0 = *reinterpret_cast<const h8*>(Pw + l16 * 64 + sg);
                h8 p1 = *reinterpret_cast<const h8*>(Pw + (16 + l16) * 64 + sg);
                #pragma unroll
                for (int dt = 0; dt < 4; ++dt) {
                    O[dt][0] = __builtin_amdgcn_mfma_f32_16x16x32_f16(vap[dt][c], p0, O[dt][0], 0, 0, 0);
                    O[dt][1] = __builtin_amdgcn_mfma_f32_16x16x32_f16(vap[dt][c], p1, O[dt][1], 0, 0, 0);
                }
            }
            __builtin_amdgcn_s_setprio(0);
        }

        if (act) {
            if (it >= 2 * ktb) {   // diagonal region: mask q > k
                #pragma unroll
                for (int nt = 0; nt < 4; ++nt)
                    #pragma unroll
                    for (int i = 0; i < 4; ++i) {
                        int q = q0 + nt * 16 + quad * 4 + i;
                        if (q > kc0) S0[nt][i] = -1e30f;
                        if (q > kc1) S1[nt][i] = -1e30f;
                    }
            }

            // tile max per column (tree, both groups interleaved)
            float mx0 = -1e30f, mx1 = -1e30f;
            #pragma unroll
            for (int nt = 0; nt < 4; ++nt) {
                float t0 = fmaxf(fmaxf(S0[nt][0], S0[nt][1]), fmaxf(S0[nt][2], S0[nt][3]));
                float t1 = fmaxf(fmaxf(S1[nt][0], S1[nt][1]), fmaxf(S1[nt][2], S1[nt][3]));
                mx0 = fmaxf(mx0, t0); mx1 = fmaxf(mx1, t1);
            }
            mx0 = fmaxf(mx0, __shfl_xor(mx0, 16)); mx1 = fmaxf(mx1, __shfl_xor(mx1, 16));
            mx0 = fmaxf(mx0, __shfl_xor(mx0, 32)); mx1 = fmaxf(mx1, __shfl_xor(mx1, 32));

            // defer-max: only rescale when some column grew past THR=8
            // (O is final w.r.t. PV(it-1) here: rescale is AFTER the deferred add)
            if (__any((mx0 - mr0 > 8.f) || (mx1 - mr1 > 8.f))) {
                float nm0 = fmaxf(mr0, mx0), nm1 = fmaxf(mr1, mx1);
                float al0 = exp2f((mr0 - nm0) * L2E), al1 = exp2f((mr1 - nm1) * L2E);
                mr0 = nm0; mr1 = nm1;
                ls0 *= al0; ls1 *= al1;
                #pragma unroll
                for (int dt = 0; dt < 4; ++dt)
                    #pragma unroll
                    for (int i = 0; i < 4; ++i) { O[dt][0][i] *= al0; O[dt][1][i] *= al1; }
            }

            const float mc0 = mr0 * L2E, mc1 = mr1 * L2E;
            float tsa = 0.f, tsb = 0.f, tsc = 0.f, tsd = 0.f;
            #pragma unroll
            for (int nt = 0; nt < 4; ++nt)
                #pragma unroll
                for (int i = 0; i < 4; ++i) {
                    float p0 = exp2f(fmaf(S0[nt][i], L2E, -mc0));
                    float p1 = exp2f(fmaf(S1[nt][i], L2E, -mc1));
                    S0[nt][i] = p0; S1[nt][i] = p1;
                    if (i & 1) { tsb += p0; tsd += p1; } else { tsa += p0; tsc += p1; }
                }
            float ts0 = tsa + tsb, ts1 = tsc + tsd;
            ts0 += __shfl_xor(ts0, 16); ts1 += __shfl_xor(ts1, 16);
            ts0 += __shfl_xor(ts0, 32); ts1 += __shfl_xor(ts1, 32);
            ls0 += ts0; ls1 += ts1;

            // P^T -> per-wave LDS (after PV(it-1)'s reads; same-wave DS is in-order)
            asm volatile("" ::: "memory");
            #pragma unroll
            for (int nt = 0; nt < 4; ++nt) {
                int sg = ((nt * 2 + (quad >> 1)) ^ (l16 & 7)) * 8 + (quad & 1) * 4;
                union { h16 hh[4]; uint2 u2; } u0, u1;
                #pragma unroll
                for (int i = 0; i < 4; ++i) { u0.hh[i] = (h16)S0[nt][i]; u1.hh[i] = (h16)S1[nt][i]; }
                *reinterpret_cast<uint2*>(Pw + l16 * 64 + sg) = u0.u2;
                *reinterpret_cast<uint2*>(Pw + (16 + l16) * 64 + sg) = u1.u2;
            }
            asm volatile("" ::: "memory");   // writes land before next iter's reads

            #pragma unroll
            for (int dt = 0; dt < 4; ++dt)
                #pragma unroll
                for (int c = 0; c < 2; ++c) vap[dt][c] = va[dt][c];
        }
    }

    // flush final PV (only if not already flushed inside the loop)
    if (nitw == nit) {
        #pragma unroll
        for (int c = 0; c < 2; ++c) {
            int sg = ((c * 4 + quad) ^ (l16 & 7)) * 8;
            h8 p0 = *reinterpret_cast<const h8*>(Pw + l16 * 64 + sg);
            h8 p1 = *reinterpret_cast<const h8*>(Pw + (16 + l16) * 64 + sg);
            #pragma unroll
            for (int dt = 0; dt < 4; ++dt) {
                O[dt][0] = __builtin_amdgcn_mfma_f32_16x16x32_f16(vap[dt][c], p0, O[dt][0], 0, 0, 0);
                O[dt][1] = __builtin_amdgcn_mfma_f32_16x16x32_f16(vap[dt][c], p1, O[dt][1], 0, 0, 0);
            }
        }
    }

    // epilogue: O cols k, rows d -> transpose via Pw, store rows of AoT
    const float inv0 = 0.03125f / ls0, inv1 = 0.03125f / ls1;
    asm volatile("" ::: "memory");
    #pragma unroll
    for (int dt = 0; dt < 4; ++dt) {
        int sg = ((dt * 2 + (quad >> 1)) ^ (l16 & 7)) * 8 + (quad & 1) * 4;
        union { h16 hh[4]; uint2 u2; } u0, u1;
        #pragma unroll
        for (int i = 0; i < 4; ++i) {
            u0.hh[i] = (h16)(O[dt][0][i] * inv0);
            u1.hh[i] = (h16)(O[dt][1][i] * inv1);
        }
        *reinterpret_cast<uint2*>(Pw + l16 * 64 + sg) = u0.u2;
        *reinterpret_cast<uint2*>(Pw + (16 + l16) * 64 + sg) = u1.u2;
    }
    asm volatile("" ::: "memory");
    #pragma unroll
    for (int g = 0; g < 2; ++g)
        #pragma unroll
        for (int j = 0; j < 2; ++j) {
            int sg = ((quad * 2 + j) ^ (l16 & 7)) * 8;
            uint4 vv = *reinterpret_cast<const uint4*>(Pw + (g * 16 + l16) * 64 + sg);
            *reinterpret_cast<uint4*>(AoT + (long)b * EW
                                      + (long)(kwave + g * 16 + l16) * E_DIM
                                      + h * 64 + quad * 16 + j * 8) = vv;
        }
}

// ---------------------------------------------------------------------------
extern "C" void kernel_launch(void* const* d_in, const int* in_sizes, int n_in,
                              void* d_out, int out_size, void* d_ws, size_t ws_size,
                              hipStream_t stream)
{
    const float* x  = (const float*)d_in[0];  // [3][B][E][W]; x[0]->K, x[1]->Q, x[2]->V
    const float* LQ = (const float*)d_in[1];
    const float* LK = (const float*)d_in[2];
    const float* LV = (const float*)d_in[3];
    const float* Mw = (const float*)d_in[4];
    const float* bb = (const float*)d_in[5];
    float* out = (float*)d_out;
    h16* ws = (h16*)d_ws;

    h16* xh  = ws;                    // [12][W][E] transposed x
    h16* LKh = ws + 12 * EW;          // weights [LK|LQ|LV|M]
    h16* Mh  = ws + 15 * EW;
    h16* Kp  = ws + 16 * EW;          // [B][W][E] (K^T)
    h16* Qp  = ws + 20 * EW;          // [B][W][E] (Q^T)
    h16* Vp  = ws + 24 * EW;          // [B][E][W] (V)
    h16* Ao  = ws + 28 * EW;          // [B][W][E] (attn out^T) = [4096][1024]

    dim3 blk(256);
    prep<<<dim3(16, 16, 16), blk, 0, stream>>>(x, LK, LQ, LV, Mw, xh, LKh);
    gemm_proj3<<<dim3(8, 8, 12), blk, 0, stream>>>(xh, LKh, Kp);
    attn_mfma<<<dim3(8, 64), blk, 0, stream>>>(Kp, Qp, Vp, Ao);
    gemm_out<<<dim3(32, 16), blk, 0, stream>>>(Mh, Ao, out, bb);
}

// Round 5
// 204.070 us; speedup vs baseline: 1.1728x; 1.1728x over previous
//
#include <hip/hip_runtime.h>
#include <stdint.h>
#include <math.h>

#define E_DIM 1024
#define W_DIM 1024
#define EW 1048576L   // 1024*1024

typedef _Float16 h16;
typedef __attribute__((ext_vector_type(8))) _Float16 h8;
typedef __attribute__((ext_vector_type(4))) float f4;

__device__ __forceinline__ void async_copy16(h16* lds, const h16* g) {
    __builtin_amdgcn_global_load_lds(
        (const __attribute__((address_space(1))) void*)g,
        (__attribute__((address_space(3))) void*)lds, 16, 0, 0);
}

// ---------------------------------------------------------------------------
// prep: z<12 -> transpose-convert x [12][E][W] fp32 -> [12][W][E] fp16;
//       z>=12 -> convert weight (z-12) fp32 -> fp16 into wh[LK|LQ|LV|M].
// ---------------------------------------------------------------------------
__global__ __launch_bounds__(256) void prep(
    const float* __restrict__ x, const float* __restrict__ LK,
    const float* __restrict__ LQ, const float* __restrict__ LV,
    const float* __restrict__ Mw, h16* __restrict__ xt, h16* __restrict__ wh)
{
    __shared__ float Ts[64][65];
    const int z = blockIdx.z;
    const int t = threadIdx.x;
    if (z < 12) {
        const float* src = x + (long)z * EW;   // [e][w]
        h16* dst = xt + (long)z * EW;          // [w][e]
        const int e0 = blockIdx.y * 64, w0 = blockIdx.x * 64;
        const int r = t >> 4, c4 = (t & 15) * 4;
        #pragma unroll
        for (int p = 0; p < 4; ++p) {
            float4 v = *reinterpret_cast<const float4*>(src + (long)(e0 + r + p * 16) * W_DIM + w0 + c4);
            Ts[c4 + 0][r + p * 16] = v.x;
            Ts[c4 + 1][r + p * 16] = v.y;
            Ts[c4 + 2][r + p * 16] = v.z;
            Ts[c4 + 3][r + p * 16] = v.w;
        }
        __syncthreads();
        #pragma unroll
        for (int p = 0; p < 4; ++p) {
            int wr = r + p * 16;
            union { h16 h[4]; uint2 u; } o;
            o.h[0] = (h16)Ts[wr][c4 + 0];
            o.h[1] = (h16)Ts[wr][c4 + 1];
            o.h[2] = (h16)Ts[wr][c4 + 2];
            o.h[3] = (h16)Ts[wr][c4 + 3];
            *reinterpret_cast<uint2*>(dst + (long)(w0 + wr) * E_DIM + e0 + c4) = o.u;
        }
    } else {
        const float* srcs[4] = {LK, LQ, LV, Mw};
        const float* s = srcs[z - 12];
        h16* o = wh + (long)(z - 12) * EW;
        long base = ((long)(blockIdx.y * 16 + blockIdx.x)) * 1024 + t;  // float4 idx
        #pragma unroll
        for (int k = 0; k < 4; ++k) {
            long i = base + k * 256;
            float4 v = reinterpret_cast<const float4*>(s)[i];
            union { h16 h[4]; uint2 u; } u;
            u.h[0] = (h16)v.x; u.h[1] = (h16)v.y; u.h[2] = (h16)v.z; u.h[3] = (h16)v.w;
            reinterpret_cast<uint2*>(o)[i] = u.u;
        }
    }
}

// ---------------------------------------------------------------------------
// Fused projection GEMMs (K, Q, V). 128x128 tile, BK=64, m97-style
// single-buffer 2-barrier K-loop (proven 633 TF), XOR-swizzled granules.
// NEW: XCD-aware bijective block remap — each XCD walks contiguous work ids,
// so a z-slice's A+B panels (4 MB) stay resident in that XCD's L2.
// ---------------------------------------------------------------------------
__global__ __launch_bounds__(256) void gemm_proj3(
    const h16* __restrict__ xh, const h16* __restrict__ Wts,
    h16* __restrict__ KQV)
{
    __shared__ h16 As[128 * 64];
    __shared__ h16 Bs[128 * 64];

    const int t = threadIdx.x;
    const int wave = t >> 6, lane = t & 63;
    const int quad = lane >> 4, l16 = lane & 15;

    // XCD swizzle: 768 wgs, 768%8==0 -> bijective chunk remap (chunk 96)
    const int lin = (int)blockIdx.x + ((int)blockIdx.y << 3) + ((int)blockIdx.z << 6);
    const int swz = (lin & 7) * 96 + (lin >> 3);
    const int bx = swz & 7, by = (swz >> 3) & 7, zz = swz >> 6;

    const int m0 = by * 128, n0 = bx * 128;
    const int wm = (wave >> 1) * 64, wn = (wave & 1) * 64;

    const int proj = zz >> 2, bz = zz & 3;
    const h16 *A, *Bt; h16* C;
    if (proj == 0)      { A = xh + bz * EW;       Bt = Wts;          C = KQV + bz * EW; }
    else if (proj == 1) { A = xh + (4 + bz) * EW; Bt = Wts + EW;     C = KQV + (4 + bz) * EW; }
    else                { A = Wts + 2 * EW;       Bt = xh + (8 + bz) * EW; C = KQV + (8 + bz) * EW; }

    f4 acc[4][4] = {};

    for (int k0 = 0; k0 < 1024; k0 += 64) {
        __syncthreads();   // prev iter's fragment reads complete
        #pragma unroll
        for (int j = 0; j < 4; ++j) {
            int g = j * 256 + t, row = g >> 3, cg = (g & 7) ^ (row & 7);
            async_copy16(&As[g * 8], A  + (long)(m0 + row) * E_DIM + k0 + cg * 8);
            async_copy16(&Bs[g * 8], Bt + (long)(n0 + row) * E_DIM + k0 + cg * 8);
        }
        __syncthreads();   // DMA drained by barrier's vmcnt(0)

        h8 av[4][2], bv[4][2];
        #pragma unroll
        for (int i = 0; i < 4; ++i) {
            int ra = wm + i * 16 + l16, rb = wn + i * 16 + l16;
            #pragma unroll
            for (int c = 0; c < 2; ++c) {
                av[i][c] = *reinterpret_cast<const h8*>(&As[(ra * 8 + ((c * 4 + quad) ^ (l16 & 7))) * 8]);
                bv[i][c] = *reinterpret_cast<const h8*>(&Bs[(rb * 8 + ((c * 4 + quad) ^ (l16 & 7))) * 8]);
            }
        }
        #pragma unroll
        for (int c = 0; c < 2; ++c)
            #pragma unroll
            for (int mt = 0; mt < 4; ++mt)
                #pragma unroll
                for (int nt = 0; nt < 4; ++nt)
                    acc[mt][nt] = __builtin_amdgcn_mfma_f32_16x16x32_f16(av[mt][c], bv[nt][c], acc[mt][nt], 0, 0, 0);
    }

    #pragma unroll
    for (int mt = 0; mt < 4; ++mt)
        #pragma unroll
        for (int i = 0; i < 4; ++i) {
            int m = m0 + wm + mt * 16 + quad * 4 + i;
            #pragma unroll
            for (int nt = 0; nt < 4; ++nt)
                C[(long)m * W_DIM + n0 + wn + nt * 16 + l16] = (h16)acc[mt][nt][i];
        }
}

// ---------------------------------------------------------------------------
// Output GEMM, batch-fused: out = M[1024x1024] x Ao[4096x1024]^T (+bias).
// RETILED to 128x128 (proj3 structure, 2x MFMA per ds_read/barrier vs 64x128),
// grid 256 blocks, single-buffer, XCD-swizzled (each XCD owns an A-row panel).
// ---------------------------------------------------------------------------
__global__ __launch_bounds__(256) void gemm_out(
    const h16* __restrict__ A, const h16* __restrict__ Bt,
    float* __restrict__ C, const float* __restrict__ bias)
{
    __shared__ h16 As[128 * 64];
    __shared__ h16 Bs[128 * 64];

    const int t = threadIdx.x;
    const int wave = t >> 6, lane = t & 63;
    const int quad = lane >> 4, l16 = lane & 15;

    // XCD swizzle: 256 wgs, chunk 32 -> each XCD gets one full by-row
    const int lin = (int)blockIdx.x + ((int)blockIdx.y << 5);
    const int swz = (lin & 7) * 32 + (lin >> 3);
    const int bx = swz & 31, by = swz >> 5;

    const int m0 = by * 128, n0 = bx * 128;
    const int wm = (wave >> 1) * 64, wn = (wave & 1) * 64;

    f4 acc[4][4] = {};

    for (int k0 = 0; k0 < 1024; k0 += 64) {
        __syncthreads();
        #pragma unroll
        for (int j = 0; j < 4; ++j) {
            int g = j * 256 + t, row = g >> 3, cg = (g & 7) ^ (row & 7);
            async_copy16(&As[g * 8], A  + (long)(m0 + row) * E_DIM + k0 + cg * 8);
            async_copy16(&Bs[g * 8], Bt + (long)(n0 + row) * E_DIM + k0 + cg * 8);
        }
        __syncthreads();

        h8 av[4][2], bv[4][2];
        #pragma unroll
        for (int i = 0; i < 4; ++i) {
            int ra = wm + i * 16 + l16, rb = wn + i * 16 + l16;
            #pragma unroll
            for (int c = 0; c < 2; ++c) {
                av[i][c] = *reinterpret_cast<const h8*>(&As[(ra * 8 + ((c * 4 + quad) ^ (l16 & 7))) * 8]);
                bv[i][c] = *reinterpret_cast<const h8*>(&Bs[(rb * 8 + ((c * 4 + quad) ^ (l16 & 7))) * 8]);
            }
        }
        #pragma unroll
        for (int c = 0; c < 2; ++c)
            #pragma unroll
            for (int mt = 0; mt < 4; ++mt)
                #pragma unroll
                for (int nt = 0; nt < 4; ++nt)
                    acc[mt][nt] = __builtin_amdgcn_mfma_f32_16x16x32_f16(av[mt][c], bv[nt][c], acc[mt][nt], 0, 0, 0);
    }

    #pragma unroll
    for (int mt = 0; mt < 4; ++mt)
        #pragma unroll
        for (int i = 0; i < 4; ++i) {
            int m = m0 + wm + mt * 16 + quad * 4 + i;
            float bv_ = bias ? bias[m] : 0.f;
            #pragma unroll
            for (int nt = 0; nt < 4; ++nt) {
                int n = n0 + wn + nt * 16 + l16;   // n = b*1024 + w
                C[(long)(n >> 10) * EW + (long)m * W_DIM + (n & 1023)] = acc[mt][nt][i] + bv_;
            }
        }
}

// ---------------------------------------------------------------------------
// MFMA flash attention (softmax over q), 128-wide k blocks — Round-1 version
// (measured 40.9 us, VGPR 96): Q/V DMA-staged double-buffered, ONE barrier
// per 64-q step; wave owns 32 k-cols (2 groups); K in regs; per-wave P^T
// LDS round trip; exp2 softmax + defer-max; complementary ktb pairing.
// ---------------------------------------------------------------------------
__global__ __launch_bounds__(256) void attn_mfma(
    const h16* __restrict__ Kt, const h16* __restrict__ Qt,
    const h16* __restrict__ V, h16* __restrict__ AoT)
{
    __shared__ h16 Qs[2][64 * 64];   // [q][d] swizzled granules
    __shared__ h16 Vs[2][64 * 64];   // [d][q] swizzled granules
    __shared__ h16 Ps[4][32 * 64];   // per-wave P^T [k32][q64] swizzled granules

    const int t = threadIdx.x, wave = t >> 6, lane = t & 63;
    const int quad = lane >> 4, l16 = lane & 15;
    const int y = blockIdx.y;
    const int b = y >> 4, h = y & 15;
    const int cxor = (y & 7) ^ (((y >> 5) & 1) ? 7 : 0);
    const int ktb = (int)blockIdx.x ^ cxor;     // 0..7; id & id+256 complementary
    const int nit = 2 * ktb + 2;
    const int kwave = ktb * 128 + wave * 32;    // wave's first k column
    const int kc0 = kwave + l16, kc1 = kc0 + 16;

    const h16* Ktb_ = Kt + (long)b * EW + h * 64;
    const h16* Qtb  = Qt + (long)b * EW + h * 64;
    const h16* Vb   = V  + (long)b * EW + (long)(h * 64) * W_DIM;
    h16* Pw = &Ps[wave][0];

    // K in registers: group g, half c -> K^T[kc_g][c*32 + quad*8 + j]
    h8 kb00 = *reinterpret_cast<const h8*>(Ktb_ + (long)kc0 * E_DIM + quad * 8);
    h8 kb01 = *reinterpret_cast<const h8*>(Ktb_ + (long)kc0 * E_DIM + 32 + quad * 8);
    h8 kb10 = *reinterpret_cast<const h8*>(Ktb_ + (long)kc1 * E_DIM + quad * 8);
    h8 kb11 = *reinterpret_cast<const h8*>(Ktb_ + (long)kc1 * E_DIM + 32 + quad * 8);

    // stage tile 0 into buf 0
    #pragma unroll
    for (int j = 0; j < 2; ++j) {
        int g = j * 256 + t, row = g >> 3, cg = (g & 7) ^ (row & 7);
        async_copy16(&Qs[0][g * 8], Qtb + (long)row * E_DIM + cg * 8);
        async_copy16(&Vs[0][g * 8], Vb + (long)row * W_DIM + cg * 8);
    }

    const float L2E = 1.442695041f;
    float mr0 = -1e30f, mr1 = -1e30f, ls0 = 0.f, ls1 = 0.f;
    f4 O[4][2] = {};

    for (int it = 0; it < nit; ++it) {
        const int q0 = it * 64;
        __syncthreads();   // drains DMA for buf it&1; prev iter's readers done
        if (it + 1 < nit) {
            const int nb = (it + 1) & 1, q1 = q0 + 64;
            #pragma unroll
            for (int j = 0; j < 2; ++j) {
                int g = j * 256 + t, row = g >> 3, cg = (g & 7) ^ (row & 7);
                async_copy16(&Qs[nb][g * 8], Qtb + (long)(q1 + row) * E_DIM + cg * 8);
                async_copy16(&Vs[nb][g * 8], Vb + (long)row * W_DIM + q1 + cg * 8);
            }
        }
        if (q0 > kwave + 31) continue;   // wave fully masked on this q-tile

        const h16* qs = Qs[it & 1];
        const h16* vs = Vs[it & 1];

        // S^T[q][k] for both k-groups; Q fragments shared
        f4 S0[4], S1[4];
        __builtin_amdgcn_s_setprio(1);
        #pragma unroll
        for (int nt = 0; nt < 4; ++nt) {
            int row = nt * 16 + l16;
            h8 a0 = *reinterpret_cast<const h8*>(&qs[(row * 8 + (quad ^ (l16 & 7))) * 8]);
            h8 a1 = *reinterpret_cast<const h8*>(&qs[(row * 8 + ((4 + quad) ^ (l16 & 7))) * 8]);
            f4 s0 = {}, s1 = {};
            s0 = __builtin_amdgcn_mfma_f32_16x16x32_f16(a0, kb00, s0, 0, 0, 0);
            s1 = __builtin_amdgcn_mfma_f32_16x16x32_f16(a0, kb10, s1, 0, 0, 0);
            s0 = __builtin_amdgcn_mfma_f32_16x16x32_f16(a1, kb01, s0, 0, 0, 0);
            s1 = __builtin_amdgcn_mfma_f32_16x16x32_f16(a1, kb11, s1, 0, 0, 0);
            S0[nt] = s0; S1[nt] = s1;
        }
        __builtin_amdgcn_s_setprio(0);

        if (it >= 2 * ktb) {   // diagonal region: mask q > k
            #pragma unroll
            for (int nt = 0; nt < 4; ++nt)
                #pragma unroll
                for (int i = 0; i < 4; ++i) {
                    int q = q0 + nt * 16 + quad * 4 + i;
                    if (q > kc0) S0[nt][i] = -1e30f;
                    if (q > kc1) S1[nt][i] = -1e30f;
                }
        }

        // tile max per column (tree, both groups interleaved)
        float mx0 = -1e30f, mx1 = -1e30f;
        #pragma unroll
        for (int nt = 0; nt < 4; ++nt) {
            float t0 = fmaxf(fmaxf(S0[nt][0], S0[nt][1]), fmaxf(S0[nt][2], S0[nt][3]));
            float t1 = fmaxf(fmaxf(S1[nt][0], S1[nt][1]), fmaxf(S1[nt][2], S1[nt][3]));
            mx0 = fmaxf(mx0, t0); mx1 = fmaxf(mx1, t1);
        }
        mx0 = fmaxf(mx0, __shfl_xor(mx0, 16)); mx1 = fmaxf(mx1, __shfl_xor(mx1, 16));
        mx0 = fmaxf(mx0, __shfl_xor(mx0, 32)); mx1 = fmaxf(mx1, __shfl_xor(mx1, 32));

        // defer-max: only rescale when some column grew past THR=8
        if (__any((mx0 - mr0 > 8.f) || (mx1 - mr1 > 8.f))) {
            float nm0 = fmaxf(mr0, mx0), nm1 = fmaxf(mr1, mx1);
            float al0 = exp2f((mr0 - nm0) * L2E), al1 = exp2f((mr1 - nm1) * L2E);
            mr0 = nm0; mr1 = nm1;
            ls0 *= al0; ls1 *= al1;
            #pragma unroll
            for (int dt = 0; dt < 4; ++dt)
                #pragma unroll
                for (int i = 0; i < 4; ++i) { O[dt][0][i] *= al0; O[dt][1][i] *= al1; }
        }

        const float mc0 = mr0 * L2E, mc1 = mr1 * L2E;
        float tsa = 0.f, tsb = 0.f, tsc = 0.f, tsd = 0.f;
        #pragma unroll
        for (int nt = 0; nt < 4; ++nt)
            #pragma unroll
            for (int i = 0; i < 4; ++i) {
                float p0 = exp2f(fmaf(S0[nt][i], L2E, -mc0));
                float p1 = exp2f(fmaf(S1[nt][i], L2E, -mc1));
                S0[nt][i] = p0; S1[nt][i] = p1;
                if (i & 1) { tsb += p0; tsd += p1; } else { tsa += p0; tsc += p1; }
            }
        float ts0 = tsa + tsb, ts1 = tsc + tsd;
        ts0 += __shfl_xor(ts0, 16); ts1 += __shfl_xor(ts1, 16);
        ts0 += __shfl_xor(ts0, 32); ts1 += __shfl_xor(ts1, 32);
        ls0 += ts0; ls1 += ts1;

        // P^T -> per-wave LDS: rows l16 (g0) and 16+l16 (g1), swizzled granules
        #pragma unroll
        for (int nt = 0; nt < 4; ++nt) {
            int sg = ((nt * 2 + (quad >> 1)) ^ (l16 & 7)) * 8 + (quad & 1) * 4;
            union { h16 hh[4]; uint2 u2; } u0, u1;
            #pragma unroll
            for (int i = 0; i < 4; ++i) { u0.hh[i] = (h16)S0[nt][i]; u1.hh[i] = (h16)S1[nt][i]; }
            *reinterpret_cast<uint2*>(Pw + l16 * 64 + sg) = u0.u2;
            *reinterpret_cast<uint2*>(Pw + (16 + l16) * 64 + sg) = u1.u2;
        }
        asm volatile("" ::: "memory");   // DS in-order per wave; read after write

        // OUT^T[d][k] += V[d][q] * P[q][k]; V fragment shared across both groups
        __builtin_amdgcn_s_setprio(1);
        #pragma unroll
        for (int c = 0; c < 2; ++c) {
            int sg = ((c * 4 + quad) ^ (l16 & 7)) * 8;
            h8 p0 = *reinterpret_cast<const h8*>(Pw + l16 * 64 + sg);
            h8 p1 = *reinterpret_cast<const h8*>(Pw + (16 + l16) * 64 + sg);
            #pragma unroll
            for (int dt = 0; dt < 4; ++dt) {
                int r = dt * 16 + l16;
                h8 va = *reinterpret_cast<const h8*>(&vs[(r * 8 + ((c * 4 + quad) ^ (l16 & 7))) * 8]);
                O[dt][0] = __builtin_amdgcn_mfma_f32_16x16x32_f16(va, p0, O[dt][0], 0, 0, 0);
                O[dt][1] = __builtin_amdgcn_mfma_f32_16x16x32_f16(va, p1, O[dt][1], 0, 0, 0);
            }
        }
        __builtin_amdgcn_s_setprio(0);
    }

    // epilogue: O cols k, rows d -> transpose via Pw, store rows of AoT
    const float inv0 = 0.03125f / ls0, inv1 = 0.03125f / ls1;
    #pragma unroll
    for (int dt = 0; dt < 4; ++dt) {
        int sg = ((dt * 2 + (quad >> 1)) ^ (l16 & 7)) * 8 + (quad & 1) * 4;
        union { h16 hh[4]; uint2 u2; } u0, u1;
        #pragma unroll
        for (int i = 0; i < 4; ++i) {
            u0.hh[i] = (h16)(O[dt][0][i] * inv0);
            u1.hh[i] = (h16)(O[dt][1][i] * inv1);
        }
        *reinterpret_cast<uint2*>(Pw + l16 * 64 + sg) = u0.u2;
        *reinterpret_cast<uint2*>(Pw + (16 + l16) * 64 + sg) = u1.u2;
    }
    asm volatile("" ::: "memory");
    #pragma unroll
    for (int g = 0; g < 2; ++g)
        #pragma unroll
        for (int j = 0; j < 2; ++j) {
            int sg = ((quad * 2 + j) ^ (l16 & 7)) * 8;
            uint4 vv = *reinterpret_cast<const uint4*>(Pw + (g * 16 + l16) * 64 + sg);
            *reinterpret_cast<uint4*>(AoT + (long)b * EW
                                      + (long)(kwave + g * 16 + l16) * E_DIM
                                      + h * 64 + quad * 16 + j * 8) = vv;
        }
}

// ---------------------------------------------------------------------------
extern "C" void kernel_launch(void* const* d_in, const int* in_sizes, int n_in,
                              void* d_out, int out_size, void* d_ws, size_t ws_size,
                              hipStream_t stream)
{
    const float* x  = (const float*)d_in[0];  // [3][B][E][W]; x[0]->K, x[1]->Q, x[2]->V
    const float* LQ = (const float*)d_in[1];
    const float* LK = (const float*)d_in[2];
    const float* LV = (const float*)d_in[3];
    const float* Mw = (const float*)d_in[4];
    const float* bb = (const float*)d_in[5];
    float* out = (float*)d_out;
    h16* ws = (h16*)d_ws;

    h16* xh  = ws;                    // [12][W][E] transposed x
    h16* LKh = ws + 12 * EW;          // weights [LK|LQ|LV|M]
    h16* Mh  = ws + 15 * EW;
    h16* Kp  = ws + 16 * EW;          // [B][W][E] (K^T)
    h16* Qp  = ws + 20 * EW;          // [B][W][E] (Q^T)
    h16* Vp  = ws + 24 * EW;          // [B][E][W] (V)
    h16* Ao  = ws + 28 * EW;          // [B][W][E] (attn out^T) = [4096][1024]

    dim3 blk(256);
    prep<<<dim3(16, 16, 16), blk, 0, stream>>>(x, LK, LQ, LV, Mw, xh, LKh);
    gemm_proj3<<<dim3(8, 8, 12), blk, 0, stream>>>(xh, LKh, Kp);
    attn_mfma<<<dim3(8, 64), blk, 0, stream>>>(Kp, Qp, Vp, Ao);
    gemm_out<<<dim3(32, 8), blk, 0, stream>>>(Mh, Ao, out, bb);
}

// Round 6
// 190.760 us; speedup vs baseline: 1.2546x; 1.0698x over previous
//
#include <hip/hip_runtime.h>
#include <stdint.h>
#include <math.h>

#define E_DIM 1024
#define W_DIM 1024
#define EW 1048576L   // 1024*1024

typedef _Float16 h16;
typedef __attribute__((ext_vector_type(8))) _Float16 h8;
typedef __attribute__((ext_vector_type(4))) float f4;

__device__ __forceinline__ void async_copy16(h16* lds, const h16* g) {
    __builtin_amdgcn_global_load_lds(
        (const __attribute__((address_space(1))) void*)g,
        (__attribute__((address_space(3))) void*)lds, 16, 0, 0);
}

// ---------------------------------------------------------------------------
// prep: z<12 -> transpose-convert x [12][E][W] fp32 -> [12][W][E] fp16;
//       z>=12 -> convert weight (z-12) fp32 -> fp16 into wh[LK|LQ|LV|M].
// ---------------------------------------------------------------------------
__global__ __launch_bounds__(256) void prep(
    const float* __restrict__ x, const float* __restrict__ LK,
    const float* __restrict__ LQ, const float* __restrict__ LV,
    const float* __restrict__ Mw, h16* __restrict__ xt, h16* __restrict__ wh)
{
    __shared__ float Ts[64][65];
    const int z = blockIdx.z;
    const int t = threadIdx.x;
    if (z < 12) {
        const float* src = x + (long)z * EW;   // [e][w]
        h16* dst = xt + (long)z * EW;          // [w][e]
        const int e0 = blockIdx.y * 64, w0 = blockIdx.x * 64;
        const int r = t >> 4, c4 = (t & 15) * 4;
        #pragma unroll
        for (int p = 0; p < 4; ++p) {
            float4 v = *reinterpret_cast<const float4*>(src + (long)(e0 + r + p * 16) * W_DIM + w0 + c4);
            Ts[c4 + 0][r + p * 16] = v.x;
            Ts[c4 + 1][r + p * 16] = v.y;
            Ts[c4 + 2][r + p * 16] = v.z;
            Ts[c4 + 3][r + p * 16] = v.w;
        }
        __syncthreads();
        #pragma unroll
        for (int p = 0; p < 4; ++p) {
            int wr = r + p * 16;
            union { h16 h[4]; uint2 u; } o;
            o.h[0] = (h16)Ts[wr][c4 + 0];
            o.h[1] = (h16)Ts[wr][c4 + 1];
            o.h[2] = (h16)Ts[wr][c4 + 2];
            o.h[3] = (h16)Ts[wr][c4 + 3];
            *reinterpret_cast<uint2*>(dst + (long)(w0 + wr) * E_DIM + e0 + c4) = o.u;
        }
    } else {
        const float* srcs[4] = {LK, LQ, LV, Mw};
        const float* s = srcs[z - 12];
        h16* o = wh + (long)(z - 12) * EW;
        long base = ((long)(blockIdx.y * 16 + blockIdx.x)) * 1024 + t;  // float4 idx
        #pragma unroll
        for (int k = 0; k < 4; ++k) {
            long i = base + k * 256;
            float4 v = reinterpret_cast<const float4*>(s)[i];
            union { h16 h[4]; uint2 u; } u;
            u.h[0] = (h16)v.x; u.h[1] = (h16)v.y; u.h[2] = (h16)v.z; u.h[3] = (h16)v.w;
            reinterpret_cast<uint2*>(o)[i] = u.u;
        }
    }
}

// ---------------------------------------------------------------------------
// Fused projection GEMMs (K, Q, V). 128x128 tile, BK=64, m97-style
// single-buffer 2-barrier K-loop, XOR-swizzled granules, XCD block remap.
// ---------------------------------------------------------------------------
__global__ __launch_bounds__(256) void gemm_proj3(
    const h16* __restrict__ xh, const h16* __restrict__ Wts,
    h16* __restrict__ KQV)
{
    __shared__ h16 As[128 * 64];
    __shared__ h16 Bs[128 * 64];

    const int t = threadIdx.x;
    const int wave = t >> 6, lane = t & 63;
    const int quad = lane >> 4, l16 = lane & 15;

    // XCD swizzle: 768 wgs, 768%8==0 -> bijective chunk remap (chunk 96)
    const int lin = (int)blockIdx.x + ((int)blockIdx.y << 3) + ((int)blockIdx.z << 6);
    const int swz = (lin & 7) * 96 + (lin >> 3);
    const int bx = swz & 7, by = (swz >> 3) & 7, zz = swz >> 6;

    const int m0 = by * 128, n0 = bx * 128;
    const int wm = (wave >> 1) * 64, wn = (wave & 1) * 64;

    const int proj = zz >> 2, bz = zz & 3;
    const h16 *A, *Bt; h16* C;
    if (proj == 0)      { A = xh + bz * EW;       Bt = Wts;          C = KQV + bz * EW; }
    else if (proj == 1) { A = xh + (4 + bz) * EW; Bt = Wts + EW;     C = KQV + (4 + bz) * EW; }
    else                { A = Wts + 2 * EW;       Bt = xh + (8 + bz) * EW; C = KQV + (8 + bz) * EW; }

    f4 acc[4][4] = {};

    for (int k0 = 0; k0 < 1024; k0 += 64) {
        __syncthreads();   // prev iter's fragment reads complete
        #pragma unroll
        for (int j = 0; j < 4; ++j) {
            int g = j * 256 + t, row = g >> 3, cg = (g & 7) ^ (row & 7);
            async_copy16(&As[g * 8], A  + (long)(m0 + row) * E_DIM + k0 + cg * 8);
            async_copy16(&Bs[g * 8], Bt + (long)(n0 + row) * E_DIM + k0 + cg * 8);
        }
        __syncthreads();   // DMA drained by barrier's vmcnt(0)

        h8 av[4][2], bv[4][2];
        #pragma unroll
        for (int i = 0; i < 4; ++i) {
            int ra = wm + i * 16 + l16, rb = wn + i * 16 + l16;
            #pragma unroll
            for (int c = 0; c < 2; ++c) {
                av[i][c] = *reinterpret_cast<const h8*>(&As[(ra * 8 + ((c * 4 + quad) ^ (l16 & 7))) * 8]);
                bv[i][c] = *reinterpret_cast<const h8*>(&Bs[(rb * 8 + ((c * 4 + quad) ^ (l16 & 7))) * 8]);
            }
        }
        #pragma unroll
        for (int c = 0; c < 2; ++c)
            #pragma unroll
            for (int mt = 0; mt < 4; ++mt)
                #pragma unroll
                for (int nt = 0; nt < 4; ++nt)
                    acc[mt][nt] = __builtin_amdgcn_mfma_f32_16x16x32_f16(av[mt][c], bv[nt][c], acc[mt][nt], 0, 0, 0);
    }

    #pragma unroll
    for (int mt = 0; mt < 4; ++mt)
        #pragma unroll
        for (int i = 0; i < 4; ++i) {
            int m = m0 + wm + mt * 16 + quad * 4 + i;
            #pragma unroll
            for (int nt = 0; nt < 4; ++nt)
                C[(long)m * W_DIM + n0 + wn + nt * 16 + l16] = (h16)acc[mt][nt][i];
        }
}

// ---------------------------------------------------------------------------
// Output GEMM, batch-fused: out = M[1024x1024] x Ao[4096x1024]^T (+bias).
// 64x128 tiles -> 512 blocks (R1-proven; 128^2 had only 256 blocks = 1/CU).
// ---------------------------------------------------------------------------
__global__ __launch_bounds__(256) void gemm_out(
    const h16* __restrict__ A, const h16* __restrict__ Bt,
    float* __restrict__ C, const float* __restrict__ bias)
{
    __shared__ h16 As[64 * 64];
    __shared__ h16 Bs[128 * 64];

    const int t = threadIdx.x;
    const int wave = t >> 6, lane = t & 63;
    const int quad = lane >> 4, l16 = lane & 15;
    const int m0 = blockIdx.y * 64, n0 = blockIdx.x * 128;
    const int wm = (wave >> 1) * 32, wn = (wave & 1) * 64;

    f4 acc[2][4] = {};

    for (int k0 = 0; k0 < 1024; k0 += 64) {
        __syncthreads();
        #pragma unroll
        for (int j = 0; j < 2; ++j) {
            int g = j * 256 + t, row = g >> 3, cg = (g & 7) ^ (row & 7);
            async_copy16(&As[g * 8], A + (long)(m0 + row) * E_DIM + k0 + cg * 8);
        }
        #pragma unroll
        for (int j = 0; j < 4; ++j) {
            int g = j * 256 + t, row = g >> 3, cg = (g & 7) ^ (row & 7);
            async_copy16(&Bs[g * 8], Bt + (long)(n0 + row) * E_DIM + k0 + cg * 8);
        }
        __syncthreads();

        h8 av[2][2], bv[4][2];
        #pragma unroll
        for (int c = 0; c < 2; ++c) {
            #pragma unroll
            for (int mt = 0; mt < 2; ++mt) {
                int r = wm + mt * 16 + l16;
                av[mt][c] = *reinterpret_cast<const h8*>(&As[(r * 8 + ((c * 4 + quad) ^ (l16 & 7))) * 8]);
            }
            #pragma unroll
            for (int nt = 0; nt < 4; ++nt) {
                int r = wn + nt * 16 + l16;
                bv[nt][c] = *reinterpret_cast<const h8*>(&Bs[(r * 8 + ((c * 4 + quad) ^ (l16 & 7))) * 8]);
            }
        }
        #pragma unroll
        for (int c = 0; c < 2; ++c)
            #pragma unroll
            for (int mt = 0; mt < 2; ++mt)
                #pragma unroll
                for (int nt = 0; nt < 4; ++nt)
                    acc[mt][nt] = __builtin_amdgcn_mfma_f32_16x16x32_f16(av[mt][c], bv[nt][c], acc[mt][nt], 0, 0, 0);
    }

    #pragma unroll
    for (int mt = 0; mt < 2; ++mt)
        #pragma unroll
        for (int i = 0; i < 4; ++i) {
            int m = m0 + wm + mt * 16 + quad * 4 + i;
            float bv_ = bias ? bias[m] : 0.f;
            #pragma unroll
            for (int nt = 0; nt < 4; ++nt) {
                int n = n0 + wn + nt * 16 + l16;   // n = b*1024 + w
                C[(long)(n >> 10) * EW + (long)m * W_DIM + (n & 1023)] = acc[mt][nt][i] + bv_;
            }
        }
}

// ---------------------------------------------------------------------------
// MFMA flash attention (softmax over q), 8-WAVE blocks (512 thr):
//  - grid (8,64): block = (b,h) x 128 k-cols; each wave owns 16 k-cols
//    (half the per-wave work of the 4-wave version, 2x the waves/CU ->
//    double occupancy for latency hiding; VGPR drops ~96 -> ~72)
//  - Q/V tiles DMA-staged double-buffered, ONE barrier per 64-q step
//  - K in regs; per-wave P^T LDS round trip (16 rows x 64, swizzled)
//  - exp2 softmax + defer-max + tree reductions; complementary ktb pairing
// ---------------------------------------------------------------------------
__global__ __launch_bounds__(512) void attn_mfma(
    const h16* __restrict__ Kt, const h16* __restrict__ Qt,
    const h16* __restrict__ V, h16* __restrict__ AoT)
{
    __shared__ h16 Qs[2][64 * 64];   // [q][d] swizzled granules (8 KB each)
    __shared__ h16 Vs[2][64 * 64];   // [d][q] swizzled granules
    __shared__ h16 Ps[8][16 * 64];   // per-wave P^T [k16][q64] swizzled granules

    const int t = threadIdx.x, wave = t >> 6, lane = t & 63;
    const int quad = lane >> 4, l16 = lane & 15;
    const int y = blockIdx.y;
    const int b = y >> 4, h = y & 15;
    const int cxor = (y & 7) ^ (((y >> 5) & 1) ? 7 : 0);
    const int ktb = (int)blockIdx.x ^ cxor;     // 0..7; id & id+256 complementary
    const int nit = 2 * ktb + 2;                // staging iterations (block-wide)
    const int kwave = ktb * 128 + wave * 16;    // wave's first k column
    const int kc = kwave + l16;                 // this lane's k column

    const h16* Ktb_ = Kt + (long)b * EW + h * 64;
    const h16* Qtb  = Qt + (long)b * EW + h * 64;
    const h16* Vb   = V  + (long)b * EW + (long)(h * 64) * W_DIM;
    h16* Pw = &Ps[wave][0];

    // K in registers: half c -> K^T[kc][c*32 + quad*8 + j]
    h8 kb0 = *reinterpret_cast<const h8*>(Ktb_ + (long)kc * E_DIM + quad * 8);
    h8 kb1 = *reinterpret_cast<const h8*>(Ktb_ + (long)kc * E_DIM + 32 + quad * 8);

    // stage tile 0 into buf 0 (512 threads x 16B = full 8 KB tile each)
    {
        int row = t >> 3, cg = (t & 7) ^ (row & 7);
        async_copy16(&Qs[0][t * 8], Qtb + (long)row * E_DIM + cg * 8);
        async_copy16(&Vs[0][t * 8], Vb + (long)row * W_DIM + cg * 8);
    }

    const float L2E = 1.442695041f;
    float mr = -1e30f, ls = 0.f;
    f4 O[4] = {};

    for (int it = 0; it < nit; ++it) {
        const int q0 = it * 64;
        __syncthreads();   // drains DMA for buf it&1; prev iter's readers done
        if (it + 1 < nit) {
            const int nb = (it + 1) & 1, q1 = q0 + 64;
            int row = t >> 3, cg = (t & 7) ^ (row & 7);
            async_copy16(&Qs[nb][t * 8], Qtb + (long)(q1 + row) * E_DIM + cg * 8);
            async_copy16(&Vs[nb][t * 8], Vb + (long)row * W_DIM + q1 + cg * 8);
        }
        if (q0 > kwave + 15) continue;   // wave fully masked on this q-tile

        const h16* qs = Qs[it & 1];
        const h16* vs = Vs[it & 1];

        // S^T[q][k]: row q = q0+nt*16+quad*4+i, col k = kc
        f4 S[4];
        __builtin_amdgcn_s_setprio(1);
        #pragma unroll
        for (int nt = 0; nt < 4; ++nt) {
            int row = nt * 16 + l16;
            h8 a0 = *reinterpret_cast<const h8*>(&qs[(row * 8 + (quad ^ (l16 & 7))) * 8]);
            h8 a1 = *reinterpret_cast<const h8*>(&qs[(row * 8 + ((4 + quad) ^ (l16 & 7))) * 8]);
            f4 s = {};
            s = __builtin_amdgcn_mfma_f32_16x16x32_f16(a0, kb0, s, 0, 0, 0);
            s = __builtin_amdgcn_mfma_f32_16x16x32_f16(a1, kb1, s, 0, 0, 0);
            S[nt] = s;
        }
        __builtin_amdgcn_s_setprio(0);

        if (it >= 2 * ktb) {   // diagonal region: mask q > k
            #pragma unroll
            for (int nt = 0; nt < 4; ++nt)
                #pragma unroll
                for (int i = 0; i < 4; ++i)
                    if (q0 + nt * 16 + quad * 4 + i > kc) S[nt][i] = -1e30f;
        }

        // tile max per column (in-lane tree + cross-quad xor16/xor32)
        float mx = -1e30f;
        #pragma unroll
        for (int nt = 0; nt < 4; ++nt) {
            float t0 = fmaxf(fmaxf(S[nt][0], S[nt][1]), fmaxf(S[nt][2], S[nt][3]));
            mx = fmaxf(mx, t0);
        }
        mx = fmaxf(mx, __shfl_xor(mx, 16));
        mx = fmaxf(mx, __shfl_xor(mx, 32));

        // defer-max: only rescale when the column max grew past THR=8
        if (__any(mx - mr > 8.f)) {
            float nm = fmaxf(mr, mx);
            float al = exp2f((mr - nm) * L2E);
            mr = nm;
            ls *= al;
            #pragma unroll
            for (int dt = 0; dt < 4; ++dt)
                #pragma unroll
                for (int i = 0; i < 4; ++i) O[dt][i] *= al;
        }

        const float mc = mr * L2E;
        float tsa = 0.f, tsb = 0.f;
        #pragma unroll
        for (int nt = 0; nt < 4; ++nt)
            #pragma unroll
            for (int i = 0; i < 4; ++i) {
                float p = exp2f(fmaf(S[nt][i], L2E, -mc));
                S[nt][i] = p;
                if (i & 1) tsb += p; else tsa += p;
            }
        float ts = tsa + tsb;
        ts += __shfl_xor(ts, 16);
        ts += __shfl_xor(ts, 32);
        ls += ts;

        // P^T -> per-wave LDS: row l16, swizzled granules
        #pragma unroll
        for (int nt = 0; nt < 4; ++nt) {
            int sg = ((nt * 2 + (quad >> 1)) ^ (l16 & 7)) * 8 + (quad & 1) * 4;
            union { h16 hh[4]; uint2 u2; } u0;
            #pragma unroll
            for (int i = 0; i < 4; ++i) u0.hh[i] = (h16)S[nt][i];
            *reinterpret_cast<uint2*>(Pw + l16 * 64 + sg) = u0.u2;
        }
        asm volatile("" ::: "memory");   // DS in-order per wave; read after write

        // OUT^T[d][k] += V[d][q] * P[q][k]
        __builtin_amdgcn_s_setprio(1);
        #pragma unroll
        for (int c = 0; c < 2; ++c) {
            int sg = ((c * 4 + quad) ^ (l16 & 7)) * 8;
            h8 pb = *reinterpret_cast<const h8*>(Pw + l16 * 64 + sg);
            #pragma unroll
            for (int dt = 0; dt < 4; ++dt) {
                int r = dt * 16 + l16;
                h8 va = *reinterpret_cast<const h8*>(&vs[(r * 8 + ((c * 4 + quad) ^ (l16 & 7))) * 8]);
                O[dt] = __builtin_amdgcn_mfma_f32_16x16x32_f16(va, pb, O[dt], 0, 0, 0);
            }
        }
        __builtin_amdgcn_s_setprio(0);
    }

    // epilogue: O cols k=l16, rows d -> transpose via Pw, store rows of AoT
    const float inv = 0.03125f / ls;
    #pragma unroll
    for (int dt = 0; dt < 4; ++dt) {
        int sg = ((dt * 2 + (quad >> 1)) ^ (l16 & 7)) * 8 + (quad & 1) * 4;
        union { h16 hh[4]; uint2 u2; } u0;
        #pragma unroll
        for (int i = 0; i < 4; ++i) u0.hh[i] = (h16)(O[dt][i] * inv);
        *reinterpret_cast<uint2*>(Pw + l16 * 64 + sg) = u0.u2;
    }
    asm volatile("" ::: "memory");
    #pragma unroll
    for (int j = 0; j < 2; ++j) {
        int sg = ((quad * 2 + j) ^ (l16 & 7)) * 8;
        uint4 vv = *reinterpret_cast<const uint4*>(Pw + l16 * 64 + sg);
        *reinterpret_cast<uint4*>(AoT + (long)b * EW + (long)(kwave + l16) * E_DIM
                                  + h * 64 + quad * 16 + j * 8) = vv;
    }
}

// ---------------------------------------------------------------------------
extern "C" void kernel_launch(void* const* d_in, const int* in_sizes, int n_in,
                              void* d_out, int out_size, void* d_ws, size_t ws_size,
                              hipStream_t stream)
{
    const float* x  = (const float*)d_in[0];  // [3][B][E][W]; x[0]->K, x[1]->Q, x[2]->V
    const float* LQ = (const float*)d_in[1];
    const float* LK = (const float*)d_in[2];
    const float* LV = (const float*)d_in[3];
    const float* Mw = (const float*)d_in[4];
    const float* bb = (const float*)d_in[5];
    float* out = (float*)d_out;
    h16* ws = (h16*)d_ws;

    h16* xh  = ws;                    // [12][W][E] transposed x
    h16* LKh = ws + 12 * EW;          // weights [LK|LQ|LV|M]
    h16* Mh  = ws + 15 * EW;
    h16* Kp  = ws + 16 * EW;          // [B][W][E] (K^T)
    h16* Qp  = ws + 20 * EW;          // [B][W][E] (Q^T)
    h16* Vp  = ws + 24 * EW;          // [B][E][W] (V)
    h16* Ao  = ws + 28 * EW;          // [B][W][E] (attn out^T) = [4096][1024]

    dim3 blk(256);
    prep<<<dim3(16, 16, 16), blk, 0, stream>>>(x, LK, LQ, LV, Mw, xh, LKh);
    gemm_proj3<<<dim3(8, 8, 12), blk, 0, stream>>>(xh, LKh, Kp);
    attn_mfma<<<dim3(8, 64), dim3(512), 0, stream>>>(Kp, Qp, Vp, Ao);
    gemm_out<<<dim3(32, 16), blk, 0, stream>>>(Mh, Ao, out, bb);
}